// Round 3
// baseline (133.639 us; speedup 1.0000x reference)
//
#include <hip/hip_runtime.h>
#include <hip/hip_bf16.h>

// out[e] = leaky( ph[src] + pg[tgt] + pu[g] + dot(ea_e, W1[128:136]) ) * W2 + b2
//   ph[i] = dot(x_h[i], W1[0:64]);  pg[j] = dot(x_g[j], W1[64:128]);
//   pu[g] = dot(u[g],  W1[136:152]) + b1.
// Fused single dispatch: phase A computes per-edge partials (held in REGISTERS)
// and streams ph/pg to workspace; device-wide barrier; phase B gathers + writes.

#define TPB 256
#define MAX_EPT 8   // max edges per thread held in registers

__device__ __forceinline__ float dot4(float4 a, float4 b) {
    return a.x * b.x + a.y * b.y + a.z * b.z + a.w * b.w;
}

__global__ void __launch_bounds__(TPB, 4)
fused_edge_model(const float* __restrict__ xh, const float* __restrict__ xg,
                 const float* __restrict__ edge_attr, const float* __restrict__ u,
                 const int* __restrict__ edge_index, const int* __restrict__ batch_e,
                 const float* __restrict__ W1, const float* __restrict__ b1,
                 const float* __restrict__ W2, const float* __restrict__ b2,
                 float* __restrict__ ph, float* __restrict__ pg,
                 unsigned* __restrict__ barrier_cnt,
                 float* __restrict__ out,
                 int nh, int ng, int ngr, int E, int nblocks) {
    __shared__ float pu_s[256];

    const int tid = blockIdx.x * TPB + threadIdx.x;
    const int NT  = nblocks * TPB;

    // --- per-block pu table in LDS (ngr <= 256 guaranteed by host) ---
    if ((int)threadIdx.x < ngr) {
        const float4* uv = reinterpret_cast<const float4*>(u + (size_t)threadIdx.x * 16);
        const float4* wu = reinterpret_cast<const float4*>(W1 + 136);
        float s = dot4(uv[0], wu[0]) + dot4(uv[1], wu[1])
                + dot4(uv[2], wu[2]) + dot4(uv[3], wu[3]);
        pu_s[threadIdx.x] = s + b1[0];
    }
    __syncthreads();

    // --- phase A1: per-edge partial (stream edge_attr + indices, keep in regs) ---
    const float* wx = W1 + 128;
    const float wx0 = wx[0], wx1 = wx[1], wx2 = wx[2], wx3 = wx[3];
    const float wx4 = wx[4], wx5 = wx[5], wx6 = wx[6], wx7 = wx[7];

    float sacc[MAX_EPT];
    int   sv[MAX_EPT];
    int   tv[MAX_EPT];
#pragma unroll
    for (int i = 0; i < MAX_EPT; ++i) {
        int e = tid + i * NT;          // coalesced: adjacent threads -> adjacent edges
        sv[i] = 0; tv[i] = 0; sacc[i] = 0.0f;
        if (e < E) {
            sv[i] = edge_index[e];
            tv[i] = edge_index[E + e];
            int g = batch_e[e];
            const float4* ea = reinterpret_cast<const float4*>(edge_attr + (size_t)e * 8);
            float4 a0 = ea[0];
            float4 a1 = ea[1];
            sacc[i] = pu_s[g]
                    + a0.x * wx0 + a0.y * wx1 + a0.z * wx2 + a0.w * wx3
                    + a1.x * wx4 + a1.y * wx5 + a1.z * wx6 + a1.w * wx7;
        }
    }

    // --- phase A2: node partial tables ph/pg (16 lanes per row, grid-stride) ---
    {
        const int group   = tid >> 4;
        const int q       = tid & 15;
        const int ngroups = NT >> 4;
        const int total   = nh + ng;
        for (int r = group; r < total; r += ngroups) {
            const float* srcp = (r < nh) ? xh + (size_t)r * 64
                                         : xg + (size_t)(r - nh) * 64;
            const float* wp   = (r < nh) ? W1 : W1 + 64;
            float4 v  = reinterpret_cast<const float4*>(srcp)[q];
            float4 wv = reinterpret_cast<const float4*>(wp)[q];
            float s = dot4(v, wv);
            s += __shfl_xor(s, 1);
            s += __shfl_xor(s, 2);
            s += __shfl_xor(s, 4);
            s += __shfl_xor(s, 8);
            if (q == 0) {
                if (r < nh) ph[r] = s;
                else        pg[r - nh] = s;
            }
        }
    }

    // --- device-wide barrier (all blocks co-resident by construction) ---
    __syncthreads();                       // drains this block's stores to L2
    if (threadIdx.x == 0) {
        __threadfence();                   // device-scope release (L2 writeback)
        __hip_atomic_fetch_add(barrier_cnt, 1u, __ATOMIC_RELEASE, __HIP_MEMORY_SCOPE_AGENT);
        while (__hip_atomic_load(barrier_cnt, __ATOMIC_ACQUIRE, __HIP_MEMORY_SCOPE_AGENT)
               < (unsigned)nblocks) {
            __builtin_amdgcn_s_sleep(8);
        }
        __threadfence();                   // acquire: invalidate stale cached lines
    }
    __syncthreads();

    // --- phase B: gather ph/pg, finalize ---
    const float w2s = W2[0], b2s = b2[0];
#pragma unroll
    for (int i = 0; i < MAX_EPT; ++i) {
        int e = tid + i * NT;
        if (e < E) {
            float h = sacc[i] + ph[sv[i]] + pg[tv[i]];
            h = (h >= 0.0f) ? h : 0.1f * h;
            out[e] = h * w2s + b2s;
        }
    }
}

// ---------------- fallback path (proven 2-kernel version) ----------------
__global__ void precompute_partials(const float* __restrict__ xh,
                                    const float* __restrict__ xg,
                                    const float* __restrict__ u,
                                    const float* __restrict__ W1,
                                    const float* __restrict__ b1,
                                    float* __restrict__ ph,
                                    float* __restrict__ pg,
                                    float* __restrict__ pu,
                                    int nh, int ng, int ngr) {
    int gid = blockIdx.x * blockDim.x + threadIdx.x;
    int row = gid >> 4;
    int q   = gid & 15;
    int total = nh + ng + ngr;
    if (row >= total) return;
    if (row < nh + ng) {
        const float* src = (row < nh) ? xh + (size_t)row * 64
                                      : xg + (size_t)(row - nh) * 64;
        const float* w   = (row < nh) ? W1 : W1 + 64;
        float4 v  = reinterpret_cast<const float4*>(src)[q];
        float4 wv = reinterpret_cast<const float4*>(w)[q];
        float s = dot4(v, wv);
        s += __shfl_xor(s, 1);
        s += __shfl_xor(s, 2);
        s += __shfl_xor(s, 4);
        s += __shfl_xor(s, 8);
        if (q == 0) {
            if (row < nh) ph[row] = s;
            else          pg[row - nh] = s;
        }
    } else {
        int g = row - nh - ng;
        float s = 0.0f;
        if (q < 4) {
            float4 v  = reinterpret_cast<const float4*>(u + (size_t)g * 16)[q];
            float4 wv = reinterpret_cast<const float4*>(W1 + 136)[q];
            s = dot4(v, wv);
        }
        s += __shfl_xor(s, 1);
        s += __shfl_xor(s, 2);
        if (q == 0) pu[g] = s + b1[0];
    }
}

__global__ void edge_kernel(const int* __restrict__ edge_index,
                            const int* __restrict__ batch_e,
                            const float* __restrict__ edge_attr,
                            const float* __restrict__ W1,
                            const float* __restrict__ W2,
                            const float* __restrict__ b2,
                            const float* __restrict__ ph,
                            const float* __restrict__ pg,
                            const float* __restrict__ pu,
                            float* __restrict__ out,
                            int E) {
    int e = blockIdx.x * blockDim.x + threadIdx.x;
    if (e >= E) return;
    int s = edge_index[e];
    int t = edge_index[E + e];
    int g = batch_e[e];
    const float4* ea = reinterpret_cast<const float4*>(edge_attr + (size_t)e * 8);
    float4 a0 = ea[0], a1 = ea[1];
    const float* wx = W1 + 128;
    float h = ph[s] + pg[t] + pu[g]
            + a0.x * wx[0] + a0.y * wx[1] + a0.z * wx[2] + a0.w * wx[3]
            + a1.x * wx[4] + a1.y * wx[5] + a1.z * wx[6] + a1.w * wx[7];
    h = (h >= 0.0f) ? h : 0.1f * h;
    out[e] = h * W2[0] + b2[0];
}

extern "C" void kernel_launch(void* const* d_in, const int* in_sizes, int n_in,
                              void* d_out, int out_size, void* d_ws, size_t ws_size,
                              hipStream_t stream) {
    const float* x_h       = (const float*)d_in[0];
    const float* x_g       = (const float*)d_in[1];
    const float* edge_attr = (const float*)d_in[2];
    const float* u         = (const float*)d_in[3];
    const int*   edge_idx  = (const int*)d_in[4];
    const int*   batch_e   = (const int*)d_in[5];
    const float* W1        = (const float*)d_in[6];
    const float* b1        = (const float*)d_in[7];
    const float* W2        = (const float*)d_in[8];
    const float* b2        = (const float*)d_in[9];
    float* out = (float*)d_out;

    const int E   = in_sizes[5];
    const int nh  = in_sizes[0] / 64;
    const int ng  = in_sizes[1] / 64;
    const int ngr = in_sizes[3] / 16;

    // workspace layout: ph[nh] | pg[ng] | counter (aligned 4B)
    size_t need = (size_t)(nh + ng) * sizeof(float) + sizeof(unsigned);

    // co-residency sizing for the fused kernel
    int perCU = 0, numCU = 0;
    hipError_t e1 = hipOccupancyMaxActiveBlocksPerMultiprocessor(
        &perCU, reinterpret_cast<const void*>(fused_edge_model), TPB, 0);
    hipError_t e2 = hipDeviceGetAttribute(&numCU, hipDeviceAttributeMultiprocessorCount, 0);

    bool fused_ok = (e1 == hipSuccess) && (e2 == hipSuccess) &&
                    (perCU > 0) && (numCU > 0) && (ngr <= 256) && (ws_size >= need);
    int nblocks = 0;
    if (fused_ok) {
        long long cap = (long long)perCU * numCU;
        nblocks = (int)((cap > 2048) ? 2048 : cap);
        long long coverage = (long long)nblocks * TPB * MAX_EPT;
        if (coverage < E) fused_ok = false;   // can't hold all edges in registers
    }

    if (fused_ok) {
        float*    ph  = (float*)d_ws;
        float*    pg  = ph + nh;
        unsigned* cnt = (unsigned*)(pg + ng);
        hipMemsetAsync(cnt, 0, sizeof(unsigned), stream);   // capture-safe
        fused_edge_model<<<nblocks, TPB, 0, stream>>>(
            x_h, x_g, edge_attr, u, edge_idx, batch_e, W1, b1, W2, b2,
            ph, pg, cnt, out, nh, ng, ngr, E, nblocks);
    } else {
        // fallback: proven 2-kernel path (needs pu[ngr] too)
        float* ph = (float*)d_ws;
        float* pg = ph + nh;
        float* pu = pg + ng;
        int totalRows = nh + ng + ngr;
        int nb = (totalRows * 16 + TPB - 1) / TPB;
        precompute_partials<<<nb, TPB, 0, stream>>>(x_h, x_g, u, W1, b1,
                                                    ph, pg, pu, nh, ng, ngr);
        int eb = (E + TPB - 1) / TPB;
        edge_kernel<<<eb, TPB, 0, stream>>>(edge_idx, batch_e, edge_attr,
                                            W1, W2, b2, ph, pg, pu, out, E);
    }
}

// Round 5
// 37.985 us; speedup vs baseline: 3.5182x; 3.5182x over previous
//
#include <hip/hip_runtime.h>
#include <hip/hip_bf16.h>

// out[e] = leaky( ph[src] + pg[tgt] + pu[g] + dot(ea_e, W1[128:136]) ) * W2 + b2
//   ph[i] = dot(x_h[i], W1[0:64]);  pg[j] = dot(x_g[j], W1[64:128]);
//   pu[g] = dot(u[g],  W1[136:152]) + b1.
// Two dispatches. NO grid barrier (R2 post-mortem: device-scope acquire spin
// forces per-XCD L2 invalidation storms -> 10x slowdown on gfx950).

#define TPB 256

// clang-native vectors: valid operands for __builtin_nontemporal_load/store
typedef float f32x4 __attribute__((ext_vector_type(4)));
typedef int   i32x4 __attribute__((ext_vector_type(4)));

__device__ __forceinline__ float dot4v(f32x4 a, f32x4 b) {
    return a.x * b.x + a.y * b.y + a.z * b.z + a.w * b.w;
}
__device__ __forceinline__ float dot4(float4 a, float4 b) {
    return a.x * b.x + a.y * b.y + a.z * b.z + a.w * b.w;
}

__device__ __forceinline__ f32x4 ntload_f4(const float* p) {
    return __builtin_nontemporal_load(reinterpret_cast<const f32x4*>(p));
}
__device__ __forceinline__ i32x4 ntload_i4(const int* p) {
    return __builtin_nontemporal_load(reinterpret_cast<const i32x4*>(p));
}

// K1: partial-dot tables. One 16-lane group per row, grid-stride.
// Streams x_h/x_g once (nontemporal); W1 stays cached.
__global__ void __launch_bounds__(TPB, 8)
precompute_partials(const float* __restrict__ xh,
                    const float* __restrict__ xg,
                    const float* __restrict__ u,
                    const float* __restrict__ W1,
                    const float* __restrict__ b1,
                    float* __restrict__ ph,
                    float* __restrict__ pg,
                    float* __restrict__ pu,
                    int nh, int ng, int ngr) {
    const int gid     = blockIdx.x * TPB + threadIdx.x;
    const int group   = gid >> 4;
    const int q       = gid & 15;
    const int ngroups = (gridDim.x * TPB) >> 4;
    const int total   = nh + ng + ngr;

    for (int r = group; r < total; r += ngroups) {
        if (r < nh + ng) {
            const float* srcp = (r < nh) ? xh + (size_t)r * 64
                                         : xg + (size_t)(r - nh) * 64;
            const float* wp   = (r < nh) ? W1 : W1 + 64;
            f32x4 v  = ntload_f4(srcp + q * 4);
            float4 wv = reinterpret_cast<const float4*>(wp)[q];
            float s = v.x * wv.x + v.y * wv.y + v.z * wv.z + v.w * wv.w;
            s += __shfl_xor(s, 1);
            s += __shfl_xor(s, 2);
            s += __shfl_xor(s, 4);
            s += __shfl_xor(s, 8);
            if (q == 0) {
                if (r < nh) ph[r] = s;
                else        pg[r - nh] = s;
            }
        } else {
            int g = r - nh - ng;
            float s = 0.0f;
            if (q < 4) {
                float4 v  = reinterpret_cast<const float4*>(u + (size_t)g * 16)[q];
                float4 wv = reinterpret_cast<const float4*>(W1 + 136)[q];
                s = dot4(v, wv);
            }
            s += __shfl_xor(s, 1);
            s += __shfl_xor(s, 2);
            if (q == 0) pu[g] = s + b1[0];
        }
    }
}

// K2: 4 edges/thread. Batch-issue all loads (indices, ea, gathers) before use.
// Nontemporal on stream-once arrays so L2 keeps ph/pg hot.
__global__ void __launch_bounds__(TPB, 8)
edge_kernel4(const int* __restrict__ edge_index,
             const int* __restrict__ batch_e,
             const float* __restrict__ edge_attr,
             const float* __restrict__ W1,
             const float* __restrict__ W2,
             const float* __restrict__ b2,
             const float* __restrict__ ph,
             const float* __restrict__ pg,
             const float* __restrict__ pu,
             float* __restrict__ out,
             int E) {
    const int t = blockIdx.x * TPB + threadIdx.x;
    const int base = t * 4;
    if (base >= E) return;

    const float* wx = W1 + 128;
    const float w0 = wx[0], w1 = wx[1], w2 = wx[2], w3 = wx[3];
    const float w4 = wx[4], w5 = wx[5], w6 = wx[6], w7 = wx[7];
    const float w2s = W2[0], b2s = b2[0];

    if (base + 3 < E) {
        i32x4 sv = ntload_i4(edge_index + base);
        i32x4 tv = ntload_i4(edge_index + E + base);
        i32x4 gv = ntload_i4(batch_e + base);

        const float* eap = edge_attr + (size_t)base * 8;
        f32x4 ea[8];
#pragma unroll
        for (int j = 0; j < 8; ++j) ea[j] = ntload_f4(eap + j * 4);

        // independent gathers issued together (MLP); ph/pg are L2-resident
        float pp[4] = {ph[sv.x], ph[sv.y], ph[sv.z], ph[sv.w]};
        float qq[4] = {pg[tv.x], pg[tv.y], pg[tv.z], pg[tv.w]};
        float rr[4] = {pu[gv.x], pu[gv.y], pu[gv.z], pu[gv.w]};

        f32x4 hv;
        float res[4];
#pragma unroll
        for (int i = 0; i < 4; ++i) {
            f32x4 a0 = ea[2 * i], a1 = ea[2 * i + 1];
            float h = pp[i] + qq[i] + rr[i]
                    + a0.x * w0 + a0.y * w1 + a0.z * w2 + a0.w * w3
                    + a1.x * w4 + a1.y * w5 + a1.z * w6 + a1.w * w7;
            h = (h >= 0.0f) ? h : 0.1f * h;
            res[i] = h * w2s + b2s;
        }
        hv.x = res[0]; hv.y = res[1]; hv.z = res[2]; hv.w = res[3];
        __builtin_nontemporal_store(hv, reinterpret_cast<f32x4*>(out + base));
    } else {
        for (int e = base; e < E; ++e) {
            int s  = edge_index[e];
            int tg = edge_index[E + e];
            int g  = batch_e[e];
            const float* a = edge_attr + (size_t)e * 8;
            float h = ph[s] + pg[tg] + pu[g]
                    + a[0] * w0 + a[1] * w1 + a[2] * w2 + a[3] * w3
                    + a[4] * w4 + a[5] * w5 + a[6] * w6 + a[7] * w7;
            h = (h >= 0.0f) ? h : 0.1f * h;
            out[e] = h * w2s + b2s;
        }
    }
}

// Fallback if workspace too small: direct gather per edge.
__global__ void edge_fallback(const int* __restrict__ edge_index,
                              const int* __restrict__ batch_e,
                              const float* __restrict__ xh,
                              const float* __restrict__ xg,
                              const float* __restrict__ edge_attr,
                              const float* __restrict__ u,
                              const float* __restrict__ W1,
                              const float* __restrict__ b1,
                              const float* __restrict__ W2,
                              const float* __restrict__ b2,
                              float* __restrict__ out,
                              int E) {
    int e = blockIdx.x * blockDim.x + threadIdx.x;
    if (e >= E) return;
    int s = edge_index[e];
    int t = edge_index[E + e];
    int g = batch_e[e];
    float h = b1[0];
    const float* hs = xh + (size_t)s * 64;
    const float* gt = xg + (size_t)t * 64;
#pragma unroll 8
    for (int j = 0; j < 64; ++j) h += hs[j] * W1[j];
#pragma unroll 8
    for (int j = 0; j < 64; ++j) h += gt[j] * W1[64 + j];
    const float* ea = edge_attr + (size_t)e * 8;
#pragma unroll
    for (int j = 0; j < 8; ++j) h += ea[j] * W1[128 + j];
    const float* ug = u + (size_t)g * 16;
#pragma unroll
    for (int j = 0; j < 16; ++j) h += ug[j] * W1[136 + j];
    h = (h >= 0.0f) ? h : 0.1f * h;
    out[e] = h * W2[0] + b2[0];
}

extern "C" void kernel_launch(void* const* d_in, const int* in_sizes, int n_in,
                              void* d_out, int out_size, void* d_ws, size_t ws_size,
                              hipStream_t stream) {
    const float* x_h       = (const float*)d_in[0];
    const float* x_g       = (const float*)d_in[1];
    const float* edge_attr = (const float*)d_in[2];
    const float* u         = (const float*)d_in[3];
    const int*   edge_idx  = (const int*)d_in[4];
    const int*   batch_e   = (const int*)d_in[5];
    const float* W1        = (const float*)d_in[6];
    const float* b1        = (const float*)d_in[7];
    const float* W2        = (const float*)d_in[8];
    const float* b2        = (const float*)d_in[9];
    float* out = (float*)d_out;

    const int E   = in_sizes[5];        // N_EDGES
    const int nh  = in_sizes[0] / 64;   // N_H_NODES
    const int ng  = in_sizes[1] / 64;   // N_G_NODES
    const int ngr = in_sizes[3] / 16;   // N_GRAPHS

    size_t need = (size_t)(nh + ng + ngr) * sizeof(float);
    if (ws_size >= need) {
        float* ph = (float*)d_ws;
        float* pg = ph + nh;
        float* pu = pg + ng;

        // K1: grid-stride, capped grid
        int totalRows = nh + ng + ngr;
        int nb = (totalRows * 16 + TPB - 1) / TPB;   // 16 lanes per row
        if (nb > 2048) nb = 2048;
        precompute_partials<<<nb, TPB, 0, stream>>>(x_h, x_g, u, W1, b1,
                                                    ph, pg, pu, nh, ng, ngr);

        int threads = (E + 3) / 4;
        int eb = (threads + TPB - 1) / TPB;
        edge_kernel4<<<eb, TPB, 0, stream>>>(edge_idx, batch_e, edge_attr,
                                             W1, W2, b2, ph, pg, pu, out, E);
    } else {
        int eb = (E + TPB - 1) / TPB;
        edge_fallback<<<eb, TPB, 0, stream>>>(edge_idx, batch_e, x_h, x_g, edge_attr, u,
                                              W1, b1, W2, b2, out, E);
    }
}

// Round 6
// 30.850 us; speedup vs baseline: 4.3318x; 1.2313x over previous
//
#include <hip/hip_runtime.h>
#include <hip/hip_bf16.h>

// Decomposition:
//   ph[i] = dot(x_h[i], W1[0:64]);  pg[j] = dot(x_g[j], W1[64:128])
//   pu[g] = dot(u[g],  W1[136:152]) + b1
//   s_e   = dot(ea_e, W1[128:136]) + pu[batch_e]          (K1, edge-role blocks)
//   out[e]= leaky(s_e + ph[src] + pg[tgt], 0.1)*W2 + b2   (K2)
// K1 role-splits blocks (edge-stream vs node-partials) -- outputs independent,
// no barrier. NO grid barriers on gfx950 (R2: L2-invalidate storm, 10x slow).
// NO nontemporal hints (R5: 31 -> 38 us regression).

#define TPB 256
#define NB_EDGE 1024   // K1 blocks doing edge partials
#define NB_NODE 1024   // K1 blocks doing node partials

typedef float f32x2 __attribute__((ext_vector_type(2)));
typedef float f32x4 __attribute__((ext_vector_type(4)));

__device__ __forceinline__ float dot4(float4 a, float4 b) {
    return a.x * b.x + a.y * b.y + a.z * b.z + a.w * b.w;
}

// K1: edge-role blocks stream edge_attr/batch_e -> s_e; node-role blocks
// build ph/pg (16 lanes per row, 1KB/wave coalesced loads).
__global__ void __launch_bounds__(TPB, 8)
k1_partials(const float* __restrict__ xh, const float* __restrict__ xg,
            const float* __restrict__ edge_attr, const float* __restrict__ u,
            const int* __restrict__ batch_e,
            const float* __restrict__ W1, const float* __restrict__ b1,
            float* __restrict__ ph, float* __restrict__ pg,
            float* __restrict__ se,
            int nh, int ng, int ngr, int E) {
    if ((int)blockIdx.x < NB_EDGE) {
        // ---- edge role: s_e = ea . wx + pu[g] ----
        __shared__ float pu_s[256];
        if ((int)threadIdx.x < ngr) {
            const float4* uv = reinterpret_cast<const float4*>(u + (size_t)threadIdx.x * 16);
            const float4* wu = reinterpret_cast<const float4*>(W1 + 136);
            float s = dot4(uv[0], wu[0]) + dot4(uv[1], wu[1])
                    + dot4(uv[2], wu[2]) + dot4(uv[3], wu[3]);
            pu_s[threadIdx.x] = s + b1[0];
        }
        __syncthreads();

        const float* wx = W1 + 128;
        const float w0 = wx[0], w1 = wx[1], w2 = wx[2], w3 = wx[3];
        const float w4 = wx[4], w5 = wx[5], w6 = wx[6], w7 = wx[7];

        const int tid    = blockIdx.x * TPB + threadIdx.x;   // 0 .. NB_EDGE*TPB
        const int stride = NB_EDGE * TPB * 2;
        for (int base = tid * 2; base < E; base += stride) {
            if (base + 1 < E) {
                const f32x4* eap = reinterpret_cast<const f32x4*>(edge_attr + (size_t)base * 8);
                f32x4 a0 = eap[0], a1 = eap[1], a2 = eap[2], a3 = eap[3];
                int2 gv = *reinterpret_cast<const int2*>(batch_e + base);
                float s0 = pu_s[gv.x]
                         + a0.x * w0 + a0.y * w1 + a0.z * w2 + a0.w * w3
                         + a1.x * w4 + a1.y * w5 + a1.z * w6 + a1.w * w7;
                float s1 = pu_s[gv.y]
                         + a2.x * w0 + a2.y * w1 + a2.z * w2 + a2.w * w3
                         + a3.x * w4 + a3.y * w5 + a3.z * w6 + a3.w * w7;
                f32x2 sv; sv.x = s0; sv.y = s1;
                *reinterpret_cast<f32x2*>(se + base) = sv;
            } else {
                const float* a = edge_attr + (size_t)base * 8;
                int g = batch_e[base];
                se[base] = pu_s[g]
                         + a[0] * w0 + a[1] * w1 + a[2] * w2 + a[3] * w3
                         + a[4] * w4 + a[5] * w5 + a[6] * w6 + a[7] * w7;
            }
        }
    } else {
        // ---- node role: ph/pg tables ----
        const int bid     = blockIdx.x - NB_EDGE;
        const int gid     = bid * TPB + threadIdx.x;
        const int group   = gid >> 4;
        const int q       = gid & 15;
        const int ngroups = (NB_NODE * TPB) >> 4;
        const int total   = nh + ng;
        for (int r = group; r < total; r += ngroups) {
            const float* srcp = (r < nh) ? xh + (size_t)r * 64
                                         : xg + (size_t)(r - nh) * 64;
            const float* wp   = (r < nh) ? W1 : W1 + 64;
            float4 v  = reinterpret_cast<const float4*>(srcp)[q];
            float4 wv = reinterpret_cast<const float4*>(wp)[q];
            float s = dot4(v, wv);
            s += __shfl_xor(s, 1);
            s += __shfl_xor(s, 2);
            s += __shfl_xor(s, 4);
            s += __shfl_xor(s, 8);
            if (q == 0) {
                if (r < nh) ph[r] = s;
                else        pg[r - nh] = s;
            }
        }
    }
}

// K2: out[e] = leaky(se[e] + ph[src] + pg[tgt]) * W2 + b2. 4 edges/thread.
__global__ void __launch_bounds__(TPB, 8)
k2_finalize(const int* __restrict__ edge_index,
            const float* __restrict__ se,
            const float* __restrict__ W2, const float* __restrict__ b2,
            const float* __restrict__ ph, const float* __restrict__ pg,
            float* __restrict__ out, int E) {
    const int t = blockIdx.x * TPB + threadIdx.x;
    const int base = t * 4;
    if (base >= E) return;

    const float w2s = W2[0], b2s = b2[0];

    if (base + 3 < E) {
        int4 sv = *reinterpret_cast<const int4*>(edge_index + base);
        int4 tv = *reinterpret_cast<const int4*>(edge_index + E + base);
        f32x4 sev = *reinterpret_cast<const f32x4*>(se + base);

        float pp[4] = {ph[sv.x], ph[sv.y], ph[sv.z], ph[sv.w]};
        float qq[4] = {pg[tv.x], pg[tv.y], pg[tv.z], pg[tv.w]};
        float s4[4] = {sev.x, sev.y, sev.z, sev.w};

        f32x4 hv;
        float res[4];
#pragma unroll
        for (int i = 0; i < 4; ++i) {
            float h = s4[i] + pp[i] + qq[i];
            h = (h >= 0.0f) ? h : 0.1f * h;
            res[i] = h * w2s + b2s;
        }
        hv.x = res[0]; hv.y = res[1]; hv.z = res[2]; hv.w = res[3];
        *reinterpret_cast<f32x4*>(out + base) = hv;
    } else {
        for (int e = base; e < E; ++e) {
            float h = se[e] + ph[edge_index[e]] + pg[edge_index[E + e]];
            h = (h >= 0.0f) ? h : 0.1f * h;
            out[e] = h * w2s + b2s;
        }
    }
}

// Fallback if workspace too small: direct gather per edge.
__global__ void edge_fallback(const int* __restrict__ edge_index,
                              const int* __restrict__ batch_e,
                              const float* __restrict__ xh,
                              const float* __restrict__ xg,
                              const float* __restrict__ edge_attr,
                              const float* __restrict__ u,
                              const float* __restrict__ W1,
                              const float* __restrict__ b1,
                              const float* __restrict__ W2,
                              const float* __restrict__ b2,
                              float* __restrict__ out,
                              int E) {
    int e = blockIdx.x * blockDim.x + threadIdx.x;
    if (e >= E) return;
    int s = edge_index[e];
    int t = edge_index[E + e];
    int g = batch_e[e];
    float h = b1[0];
    const float* hs = xh + (size_t)s * 64;
    const float* gt = xg + (size_t)t * 64;
#pragma unroll 8
    for (int j = 0; j < 64; ++j) h += hs[j] * W1[j];
#pragma unroll 8
    for (int j = 0; j < 64; ++j) h += gt[j] * W1[64 + j];
    const float* ea = edge_attr + (size_t)e * 8;
#pragma unroll
    for (int j = 0; j < 8; ++j) h += ea[j] * W1[128 + j];
    const float* ug = u + (size_t)g * 16;
#pragma unroll
    for (int j = 0; j < 16; ++j) h += ug[j] * W1[136 + j];
    h = (h >= 0.0f) ? h : 0.1f * h;
    out[e] = h * W2[0] + b2[0];
}

extern "C" void kernel_launch(void* const* d_in, const int* in_sizes, int n_in,
                              void* d_out, int out_size, void* d_ws, size_t ws_size,
                              hipStream_t stream) {
    const float* x_h       = (const float*)d_in[0];
    const float* x_g       = (const float*)d_in[1];
    const float* edge_attr = (const float*)d_in[2];
    const float* u         = (const float*)d_in[3];
    const int*   edge_idx  = (const int*)d_in[4];
    const int*   batch_e   = (const int*)d_in[5];
    const float* W1        = (const float*)d_in[6];
    const float* b1        = (const float*)d_in[7];
    const float* W2        = (const float*)d_in[8];
    const float* b2        = (const float*)d_in[9];
    float* out = (float*)d_out;

    const int E   = in_sizes[5];        // N_EDGES
    const int nh  = in_sizes[0] / 64;   // N_H_NODES
    const int ng  = in_sizes[1] / 64;   // N_G_NODES
    const int ngr = in_sizes[3] / 16;   // N_GRAPHS

    // ws layout: ph[nh] | pg[ng] | se[E]
    size_t need = ((size_t)nh + ng + E) * sizeof(float);
    if (ws_size >= need && ngr <= 256) {
        float* ph = (float*)d_ws;
        float* pg = ph + nh;
        float* se = pg + ng;

        k1_partials<<<NB_EDGE + NB_NODE, TPB, 0, stream>>>(
            x_h, x_g, edge_attr, u, batch_e, W1, b1, ph, pg, se,
            nh, ng, ngr, E);

        int threads = (E + 3) / 4;
        int eb = (threads + TPB - 1) / TPB;
        k2_finalize<<<eb, TPB, 0, stream>>>(edge_idx, se, W2, b2, ph, pg, out, E);
    } else {
        int eb = (E + TPB - 1) / TPB;
        edge_fallback<<<eb, TPB, 0, stream>>>(edge_idx, batch_e, x_h, x_g, edge_attr, u,
                                              W1, b1, W2, b2, out, E);
    }
}